// Round 12
// baseline (39.989 us; speedup 1.0000x reference)
//
#include <hip/hip_runtime.h>

#define NK 512
#define NC 256
#define NH 200
#define NW 200
#define PLANE (NH * NW)
#define RSCALE 0.0625f
#define NT 64                // one wave per block
#define TAB_STRIDE 40        // float4s per roi table (640 B)
#define TAB_BYTES (NK * TAB_STRIDE * 16)   // 320 KB

// ---------------- Kernel 1: per-roi tables -> d_ws -------------------------
// Layout per roi (float4 slots, stride 40):
//   [0..10]  W[pw]      combined 4-wide x-weights (validity folded)
//   [11..21] wy[ph]     0.25 * vy * (hy|ly)
//   [22..32] yrel[ph]   int4, (row - ymin) * 11
//   [33..35] ints xb[0..10] + ymin   (xb packed 4-per-slot; slot35.w = ymin)
//   [36]     ints {nrows, b, 0, 0}
__global__ __launch_bounds__(NT) void build_tables(
    const float* __restrict__ rois, float4* __restrict__ tab)
{
    const int k = blockIdx.x;
    const int t = threadIdx.x;
    if (t >= 22) return;

    const float rx1 = rois[k * 5 + 1] * RSCALE;
    const float ry1 = rois[k * 5 + 2] * RSCALE;
    const float rx2 = rois[k * 5 + 3] * RSCALE;
    const float ry2 = rois[k * 5 + 4] * RSCALE;
    const float bin_w = fmaxf(rx2 - rx1, 1.0f) / 11.0f;
    const float bin_h = fmaxf(ry2 - ry1, 1.0f) / 11.0f;

    const int d = t / 11;            // 0 = x, 1 = y
    const int pbin = t % 11;
    const float start = d ? ry1 : rx1;
    const float bs    = d ? bin_h : bin_w;
    const int   lim   = d ? NH : NW;
    const float p = (float)pbin;
    // sub-sample coords, same expression order as reference
    float cv0 = start + (p + 0.25f) * bs;   // (0+0.5)/2
    float cv1 = start + (p + 0.75f) * bs;   // (1+0.5)/2
    const float va0 = (cv0 > -1.0f && cv0 < (float)lim) ? 1.0f : 0.0f;
    const float va1 = (cv1 > -1.0f && cv1 < (float)lim) ? 1.0f : 0.0f;
    cv0 = fminf(fmaxf(cv0, 0.0f), (float)(lim - 1));
    cv1 = fminf(fmaxf(cv1, 0.0f), (float)(lim - 1));
    const int lo0 = (int)floorf(cv0);
    const int lo1 = (int)floorf(cv1);
    const int hi0 = min(lo0 + 1, lim - 1);
    const int hi1 = min(lo1 + 1, lim - 1);
    const float fr0 = cv0 - (float)lo0;
    const float fr1 = cv1 - (float)lo1;

    float4* tb = tab + k * TAB_STRIDE;
    if (d == 0) {
        const int xb = min(lo0, NW - 4);     // 4-col window base (lo1<=lo0+2)
        const int a0 = lo0 - xb, a1 = hi0 - xb, a2 = lo1 - xb, a3 = hi1 - xb;
        const float w0 = va0 * (1.0f - fr0), w1 = va0 * fr0;
        const float w2 = va1 * (1.0f - fr1), w3 = va1 * fr1;
        float W[4];
        #pragma unroll
        for (int jj = 0; jj < 4; ++jj) {
            // same contribution order as the original sequential += chain
            float v = (a0 == jj) ? w0 : 0.0f;
            v += (a1 == jj) ? w1 : 0.0f;
            v += (a2 == jj) ? w2 : 0.0f;
            v += (a3 == jj) ? w3 : 0.0f;
            W[jj] = v;
        }
        tb[pbin] = make_float4(W[0], W[1], W[2], W[3]);
        ((int*)(tb + 33))[pbin] = xb;        // ints 0..10 across slots 33..35
        if (pbin == 0) {
            // y-extent: rows monotone in (ph,sub); same expr order as y lanes
            float cy0 = ry1 + (0.0f + 0.25f) * bin_h;
            cy0 = fminf(fmaxf(cy0, 0.0f), (float)(NH - 1));
            const int ymin = (int)floorf(cy0);
            float cyL = ry1 + (10.0f + 0.75f) * bin_h;
            cyL = fminf(fmaxf(cyL, 0.0f), (float)(NH - 1));
            const int ymax = min((int)floorf(cyL) + 1, NH - 1);
            ((int*)(tb + 33))[11] = ymin;               // slot35.w
            ((int*)(tb + 36))[0]  = ymax - ymin + 1;    // nrows
            ((int*)(tb + 36))[1]  = (int)rois[k * 5 + 0];
        }
    } else {
        // ymin recomputed identically
        float cy0 = ry1 + (0.0f + 0.25f) * bin_h;
        cy0 = fminf(fmaxf(cy0, 0.0f), (float)(NH - 1));
        const int ymin = (int)floorf(cy0);
        ((int4*)(tb + 22))[pbin] = make_int4((lo0 - ymin) * 11, (hi0 - ymin) * 11,
                                             (lo1 - ymin) * 11, (hi1 - ymin) * 11);
        tb[11 + pbin] = make_float4(0.25f * va0 * (1.0f - fr0), 0.25f * va0 * fr0,
                                    0.25f * va1 * (1.0f - fr1), 0.25f * va1 * fr1);
    }
}

// ---------------- Kernel 2: main (tables from d_ws) ------------------------
// One block = ONE WAVE = one (roi k, channel pair cp). 65536 blocks, XCD-pinned
// (xcd = blk&7 matches dispatch round-robin; cp = local*8 + xcd). Table fill:
// lanes 0-36 load one float4 each (L2-broadcast across the roi's 128 blocks).
__global__ __launch_bounds__(NT) void roi_align_maxpool(
    const float* __restrict__ feat,   // (B, C, H, W) f32
    const float4* __restrict__ tab,   // per-roi tables
    float* __restrict__ out)          // (K, C, 5, 5)
{
    __shared__ float4 s_tab[37];
    __shared__ float  s_xdot[2][352];    // [ch][rel*11+pw]
    __shared__ float  s_pool[2][121];

    const int blk = blockIdx.x;
    const int xcd = blk & 7;             // dispatch: blk % 8 -> XCD id
    const int j   = blk >> 3;
    const int k   = j & (NK - 1);        // roi, fast within an XCD's stream
    const int cp  = ((j >> 9) << 3) | xcd;   // channel pair pinned to this XCD
    const int t   = threadIdx.x;

    if (t < 37) s_tab[t] = tab[k * TAB_STRIDE + t];
    __syncthreads();   // single-wave workgroup: waitcnt only

    const float*  s_W    = (const float*)(s_tab);         // [11][4]
    const float4* s_wy   = s_tab + 11;                    // [11]
    const int4*   s_yrel = (const int4*)(s_tab + 22);     // [11]
    const int*    s_xb   = (const int*)(s_tab + 33);      // [11], [11]=ymin
    const int ymin  = s_xb[11];
    const int nrows = ((const int*)(s_tab + 36))[0];
    const int b     = ((const int*)(s_tab + 36))[1];

    // Phase A: task q = rel*11 + pw (= xdot slot), both channels per task.
    {
        const float* fbase = feat + (size_t)(b * NC + cp * 2) * PLANE;
        const int ntask = nrows * 11;
        for (int q = t; q < ntask; q += NT) {
            const int rel = q / 11;
            const int pw  = q - rel * 11;
            const int    xb = s_xb[pw];
            const float4 W  = *(const float4*)(s_W + pw * 4);
            const float* p0 = fbase + (ymin + rel) * NW + xb;
            const float4 v0 = *(const float4*)p0;             // ch = 2cp
            const float4 v1 = *(const float4*)(p0 + PLANE);   // ch = 2cp+1
            float d0 = v0.x * W.x; d0 = fmaf(v0.y, W.y, d0); d0 = fmaf(v0.z, W.z, d0); d0 = fmaf(v0.w, W.w, d0);
            float d1 = v1.x * W.x; d1 = fmaf(v1.y, W.y, d1); d1 = fmaf(v1.z, W.z, d1); d1 = fmaf(v1.w, W.w, d1);
            s_xdot[0][q] = d0;
            s_xdot[1][q] = d1;
        }
    }
    __syncthreads();

    // Phase B: pooled bin = sum_r wy[r] * xdot[row_r][pw], both channels
    for (int q = t; q < 121; q += NT) {
        const int ph = q / 11;
        const int pw = q - ph * 11;
        const int4   yr = s_yrel[ph];
        const float4 wy = s_wy[ph];
        const float* xd0 = &s_xdot[0][pw];
        const float* xd1 = &s_xdot[1][pw];
        float b0 = wy.x * xd0[yr.x];
        b0 = fmaf(wy.y, xd0[yr.y], b0);
        b0 = fmaf(wy.z, xd0[yr.z], b0);
        b0 = fmaf(wy.w, xd0[yr.w], b0);
        float b1 = wy.x * xd1[yr.x];
        b1 = fmaf(wy.y, xd1[yr.y], b1);
        b1 = fmaf(wy.z, xd1[yr.z], b1);
        b1 = fmaf(wy.w, xd1[yr.w], b1);
        s_pool[0][q] = b0;   // 0.25 mean folded into wy
        s_pool[1][q] = b1;
    }
    __syncthreads();

    // Phase C: 3x3/stride2 max-pool, contiguous 50-float store per block
    if (t < 50) {
        const int ch = t / 25;
        const int r  = t % 25;
        const int oh = r / 5, ow = r % 5;
        float m = -INFINITY;
        #pragma unroll
        for (int dy = 0; dy < 3; ++dy)
            #pragma unroll
            for (int dx = 0; dx < 3; ++dx)
                m = fmaxf(m, s_pool[ch][(2 * oh + dy) * 11 + (2 * ow + dx)]);
        out[((size_t)k * NC + cp * 2) * 25 + t] = m;
    }
}

// ---------------- Fallback (R11 single-kernel, no workspace) ---------------
__global__ __launch_bounds__(NT) void roi_align_maxpool_fb(
    const float* __restrict__ feat, const float* __restrict__ rois,
    float* __restrict__ out)
{
    __shared__ float s_xdot[2][352];
    __shared__ float s_pool[2][121];
    __shared__ int   s_xb[11];
    __shared__ float s_W [11][4];
    __shared__ int   s_yrel[11][4];
    __shared__ float s_wy[11][4];

    const int blk = blockIdx.x;
    const int xcd = blk & 7;
    const int j   = blk >> 3;
    const int k   = j & (NK - 1);
    const int cp  = ((j >> 9) << 3) | xcd;
    const int t   = threadIdx.x;

    const float rx1 = rois[k * 5 + 1] * RSCALE;
    const float ry1 = rois[k * 5 + 2] * RSCALE;
    const float rx2 = rois[k * 5 + 3] * RSCALE;
    const float ry2 = rois[k * 5 + 4] * RSCALE;
    const int   b   = (int)rois[k * 5 + 0];
    const float bin_w = fmaxf(rx2 - rx1, 1.0f) / 11.0f;
    const float bin_h = fmaxf(ry2 - ry1, 1.0f) / 11.0f;

    float cy0 = ry1 + (0.0f + 0.25f) * bin_h;
    cy0 = fminf(fmaxf(cy0, 0.0f), (float)(NH - 1));
    const int ymin = (int)floorf(cy0);
    float cyL = ry1 + (10.0f + 0.75f) * bin_h;
    cyL = fminf(fmaxf(cyL, 0.0f), (float)(NH - 1));
    const int nrows = min((int)floorf(cyL) + 1, NH - 1) - ymin + 1;

    if (t < 22) {
        const int d = t / 11;
        const int pbin = t % 11;
        const float start = d ? ry1 : rx1;
        const float bs    = d ? bin_h : bin_w;
        const int   lim   = d ? NH : NW;
        const float p = (float)pbin;
        float cv0 = start + (p + 0.25f) * bs;
        float cv1 = start + (p + 0.75f) * bs;
        const float va0 = (cv0 > -1.0f && cv0 < (float)lim) ? 1.0f : 0.0f;
        const float va1 = (cv1 > -1.0f && cv1 < (float)lim) ? 1.0f : 0.0f;
        cv0 = fminf(fmaxf(cv0, 0.0f), (float)(lim - 1));
        cv1 = fminf(fmaxf(cv1, 0.0f), (float)(lim - 1));
        const int lo0 = (int)floorf(cv0);
        const int lo1 = (int)floorf(cv1);
        const int hi0 = min(lo0 + 1, lim - 1);
        const int hi1 = min(lo1 + 1, lim - 1);
        const float fr0 = cv0 - (float)lo0;
        const float fr1 = cv1 - (float)lo1;
        if (d == 0) {
            const int xb = min(lo0, NW - 4);
            s_xb[pbin] = xb;
            s_W[pbin][0] = 0.0f; s_W[pbin][1] = 0.0f;
            s_W[pbin][2] = 0.0f; s_W[pbin][3] = 0.0f;
            s_W[pbin][lo0 - xb] += va0 * (1.0f - fr0);
            s_W[pbin][hi0 - xb] += va0 * fr0;
            s_W[pbin][lo1 - xb] += va1 * (1.0f - fr1);
            s_W[pbin][hi1 - xb] += va1 * fr1;
        } else {
            s_yrel[pbin][0] = (lo0 - ymin) * 11;
            s_yrel[pbin][1] = (hi0 - ymin) * 11;
            s_yrel[pbin][2] = (lo1 - ymin) * 11;
            s_yrel[pbin][3] = (hi1 - ymin) * 11;
            s_wy[pbin][0] = 0.25f * va0 * (1.0f - fr0);
            s_wy[pbin][1] = 0.25f * va0 * fr0;
            s_wy[pbin][2] = 0.25f * va1 * (1.0f - fr1);
            s_wy[pbin][3] = 0.25f * va1 * fr1;
        }
    }
    __syncthreads();

    {
        const float* fbase = feat + (size_t)(b * NC + cp * 2) * PLANE;
        const int ntask = nrows * 11;
        for (int q = t; q < ntask; q += NT) {
            const int rel = q / 11;
            const int pw  = q - rel * 11;
            const int    xb = s_xb[pw];
            const float4 W  = *(const float4*)s_W[pw];
            const float* p0 = fbase + (ymin + rel) * NW + xb;
            const float4 v0 = *(const float4*)p0;
            const float4 v1 = *(const float4*)(p0 + PLANE);
            float d0 = v0.x * W.x; d0 = fmaf(v0.y, W.y, d0); d0 = fmaf(v0.z, W.z, d0); d0 = fmaf(v0.w, W.w, d0);
            float d1 = v1.x * W.x; d1 = fmaf(v1.y, W.y, d1); d1 = fmaf(v1.z, W.z, d1); d1 = fmaf(v1.w, W.w, d1);
            s_xdot[0][q] = d0;
            s_xdot[1][q] = d1;
        }
    }
    __syncthreads();

    for (int q = t; q < 121; q += NT) {
        const int ph = q / 11;
        const int pw = q - ph * 11;
        const int4   yr = *(const int4*)s_yrel[ph];
        const float4 wy = *(const float4*)s_wy[ph];
        const float* xd0 = &s_xdot[0][pw];
        const float* xd1 = &s_xdot[1][pw];
        float b0 = wy.x * xd0[yr.x];
        b0 = fmaf(wy.y, xd0[yr.y], b0);
        b0 = fmaf(wy.z, xd0[yr.z], b0);
        b0 = fmaf(wy.w, xd0[yr.w], b0);
        float b1 = wy.x * xd1[yr.x];
        b1 = fmaf(wy.y, xd1[yr.y], b1);
        b1 = fmaf(wy.z, xd1[yr.z], b1);
        b1 = fmaf(wy.w, xd1[yr.w], b1);
        s_pool[0][q] = b0;
        s_pool[1][q] = b1;
    }
    __syncthreads();

    if (t < 50) {
        const int ch = t / 25;
        const int r  = t % 25;
        const int oh = r / 5, ow = r % 5;
        float m = -INFINITY;
        #pragma unroll
        for (int dy = 0; dy < 3; ++dy)
            #pragma unroll
            for (int dx = 0; dx < 3; ++dx)
                m = fmaxf(m, s_pool[ch][(2 * oh + dy) * 11 + (2 * ow + dx)]);
        out[((size_t)k * NC + cp * 2) * 25 + t] = m;
    }
}

extern "C" void kernel_launch(void* const* d_in, const int* in_sizes, int n_in,
                              void* d_out, int out_size, void* d_ws, size_t ws_size,
                              hipStream_t stream) {
    const float* feat = (const float*)d_in[0];   // (4, 256, 200, 200) f32
    const float* rois = (const float*)d_in[1];   // (512, 5) f32
    float* out = (float*)d_out;                  // (512, 256, 5, 5) f32

    const int nblocks = NK * (NC / 2);           // 65536 single-wave blocks
    if (ws_size >= (size_t)TAB_BYTES && d_ws != nullptr) {
        float4* tab = (float4*)d_ws;
        build_tables<<<NK, NT, 0, stream>>>(rois, tab);
        roi_align_maxpool<<<nblocks, NT, 0, stream>>>(feat, tab, out);
    } else {
        roi_align_maxpool_fb<<<nblocks, NT, 0, stream>>>(feat, rois, out);
    }
}

// Round 13
// 39.124 us; speedup vs baseline: 1.0221x; 1.0221x over previous
//
#include <hip/hip_runtime.h>

#define NK 512
#define NC 256
#define NH 200
#define NW 200
#define PLANE (NH * NW)
#define RSCALE 0.0625f
#define NT 64                // one wave per block -> __syncthreads() is waitcnt-only

// FINAL (R11 revert, best measured: 39.0 us harness).
// One block = ONE WAVE = one (roi k, channel pair cp -> channels 2cp, 2cp+1).
// 65536 blocks. No cross-wave synchronization: single-wave workgroups make
// every __syncthreads() waitcnt-only, waves fully independent, 32/CU
// co-resident (LDS 4.4KB/block) -> maximal latency hiding, zero barrier drain.
// XCD pinning (xcd = blk&7 matches dispatch round-robin): cp = local*8 + xcd;
// resident working set per XCD = 4 ch x 4 batches x 160KB = 2.56MB < 4MB L2.
// Phase 0: lanes 0-21 build per-bin tables (LDS, wave-coherent).
// Phase A: xdot[ch][rel*11+pw] = dot4(feat row window, W[pw]); nrows*11 tasks,
//          each loading both channels (+PLANE) -> 2 float4 loads, 8 FMA.
// Phase B: pooled bin = sum_r wy[r]*xdot[row_r][pw], both channels.
// Phase C: 50 lanes 3x3/stride2 max-pool -> contiguous 50-float store.
__global__ __launch_bounds__(NT) void roi_align_maxpool(
    const float* __restrict__ feat,   // (B, C, H, W) f32
    const float* __restrict__ rois,   // (K, 5)
    float* __restrict__ out)          // (K, C, 5, 5)
{
    __shared__ float s_xdot[2][352];     // [ch][rel*11+pw]
    __shared__ float s_pool[2][121];
    __shared__ int   s_xb[11];           // absolute base col of 4-col window
    __shared__ float s_W [11][4];        // combined x-weights (validity folded)
    __shared__ int   s_yrel[11][4];      // (row - ymin) * 11
    __shared__ float s_wy[11][4];        // 0.25 * vy * (hy|ly)

    const int blk = blockIdx.x;
    const int xcd = blk & 7;             // dispatch: blk % 8 -> XCD id
    const int j   = blk >> 3;
    const int k   = j & (NK - 1);        // roi, fast within an XCD's stream
    const int cp  = ((j >> 9) << 3) | xcd;   // channel pair pinned to this XCD
    const int t   = threadIdx.x;

    // Uniform roi params (wave-uniform scalar loads, L1/L2 broadcast)
    const float rx1 = rois[k * 5 + 1] * RSCALE;
    const float ry1 = rois[k * 5 + 2] * RSCALE;
    const float rx2 = rois[k * 5 + 3] * RSCALE;
    const float ry2 = rois[k * 5 + 4] * RSCALE;
    const int   b   = (int)rois[k * 5 + 0];
    const float bin_w = fmaxf(rx2 - rx1, 1.0f) / 11.0f;
    const float bin_h = fmaxf(ry2 - ry1, 1.0f) / 11.0f;

    // Uniform y-extent (rows monotone in (ph,sub)); expressions bitwise-match
    // the table lanes: start + (p + g)*bs with constant-folded (p+g).
    float cy0 = ry1 + 0.25f * bin_h;                   // (0 + 0.25)
    cy0 = fminf(fmaxf(cy0, 0.0f), (float)(NH - 1));
    const int ymin = (int)floorf(cy0);
    float cyL = ry1 + 10.75f * bin_h;                  // (10 + 0.75)
    cyL = fminf(fmaxf(cyL, 0.0f), (float)(NH - 1));
    const int nrows = min((int)floorf(cyL) + 1, NH - 1) - ymin + 1;  // 2..32

    if (t < 22) {
        const int d = t / 11;            // 0 = x, 1 = y
        const int pbin = t % 11;
        const float start = d ? ry1 : rx1;
        const float bs    = d ? bin_h : bin_w;
        const int   lim   = d ? NH : NW;
        const float p = (float)pbin;
        // sub-sample coords, same expression order as reference
        float cv0 = start + (p + 0.25f) * bs;   // (0+0.5)/2
        float cv1 = start + (p + 0.75f) * bs;   // (1+0.5)/2
        const float va0 = (cv0 > -1.0f && cv0 < (float)lim) ? 1.0f : 0.0f;
        const float va1 = (cv1 > -1.0f && cv1 < (float)lim) ? 1.0f : 0.0f;
        cv0 = fminf(fmaxf(cv0, 0.0f), (float)(lim - 1));
        cv1 = fminf(fmaxf(cv1, 0.0f), (float)(lim - 1));
        const int lo0 = (int)floorf(cv0);
        const int lo1 = (int)floorf(cv1);
        const int hi0 = min(lo0 + 1, lim - 1);
        const int hi1 = min(lo1 + 1, lim - 1);
        const float fr0 = cv0 - (float)lo0;
        const float fr1 = cv1 - (float)lo1;
        if (d == 0) {
            const int xb = min(lo0, NW - 4);    // 4-col window base (lo1<=lo0+2)
            s_xb[pbin] = xb;
            s_W[pbin][0] = 0.0f; s_W[pbin][1] = 0.0f;
            s_W[pbin][2] = 0.0f; s_W[pbin][3] = 0.0f;
            s_W[pbin][lo0 - xb] += va0 * (1.0f - fr0);
            s_W[pbin][hi0 - xb] += va0 * fr0;
            s_W[pbin][lo1 - xb] += va1 * (1.0f - fr1);
            s_W[pbin][hi1 - xb] += va1 * fr1;
        } else {
            s_yrel[pbin][0] = (lo0 - ymin) * 11;
            s_yrel[pbin][1] = (hi0 - ymin) * 11;
            s_yrel[pbin][2] = (lo1 - ymin) * 11;
            s_yrel[pbin][3] = (hi1 - ymin) * 11;
            s_wy[pbin][0] = 0.25f * va0 * (1.0f - fr0);
            s_wy[pbin][1] = 0.25f * va0 * fr0;
            s_wy[pbin][2] = 0.25f * va1 * (1.0f - fr1);
            s_wy[pbin][3] = 0.25f * va1 * fr1;
        }
    }
    __syncthreads();   // single-wave workgroup: waitcnt only, no barrier stall

    // Phase A: task q = rel*11 + pw (= xdot slot), both channels per task.
    {
        const float* fbase = feat + (size_t)(b * NC + cp * 2) * PLANE;
        const int ntask = nrows * 11;
        for (int q = t; q < ntask; q += NT) {
            const int rel = q / 11;
            const int pw  = q - rel * 11;
            const int    xb = s_xb[pw];
            const float4 W  = *(const float4*)s_W[pw];
            const float* p0 = fbase + (ymin + rel) * NW + xb;
            const float4 v0 = *(const float4*)p0;             // ch = 2cp
            const float4 v1 = *(const float4*)(p0 + PLANE);   // ch = 2cp+1
            float d0 = v0.x * W.x; d0 = fmaf(v0.y, W.y, d0); d0 = fmaf(v0.z, W.z, d0); d0 = fmaf(v0.w, W.w, d0);
            float d1 = v1.x * W.x; d1 = fmaf(v1.y, W.y, d1); d1 = fmaf(v1.z, W.z, d1); d1 = fmaf(v1.w, W.w, d1);
            s_xdot[0][q] = d0;
            s_xdot[1][q] = d1;
        }
    }
    __syncthreads();

    // Phase B: pooled bin = sum_r wy[r] * xdot[row_r][pw], both channels
    for (int q = t; q < 121; q += NT) {
        const int ph = q / 11;
        const int pw = q - ph * 11;
        const int4   yr = *(const int4*)s_yrel[ph];
        const float4 wy = *(const float4*)s_wy[ph];
        const float* xd0 = &s_xdot[0][pw];
        const float* xd1 = &s_xdot[1][pw];
        float b0 = wy.x * xd0[yr.x];
        b0 = fmaf(wy.y, xd0[yr.y], b0);
        b0 = fmaf(wy.z, xd0[yr.z], b0);
        b0 = fmaf(wy.w, xd0[yr.w], b0);
        float b1 = wy.x * xd1[yr.x];
        b1 = fmaf(wy.y, xd1[yr.y], b1);
        b1 = fmaf(wy.z, xd1[yr.z], b1);
        b1 = fmaf(wy.w, xd1[yr.w], b1);
        s_pool[0][q] = b0;   // 0.25 mean folded into wy
        s_pool[1][q] = b1;
    }
    __syncthreads();

    // Phase C: 3x3/stride2 max-pool, contiguous 50-float store per block
    if (t < 50) {
        const int ch = t / 25;
        const int r  = t % 25;
        const int oh = r / 5, ow = r % 5;
        float m = -INFINITY;
        #pragma unroll
        for (int dy = 0; dy < 3; ++dy)
            #pragma unroll
            for (int dx = 0; dx < 3; ++dx)
                m = fmaxf(m, s_pool[ch][(2 * oh + dy) * 11 + (2 * ow + dx)]);
        out[((size_t)k * NC + cp * 2) * 25 + t] = m;
    }
}

extern "C" void kernel_launch(void* const* d_in, const int* in_sizes, int n_in,
                              void* d_out, int out_size, void* d_ws, size_t ws_size,
                              hipStream_t stream) {
    const float* feat = (const float*)d_in[0];   // (4, 256, 200, 200) f32
    const float* rois = (const float*)d_in[1];   // (512, 5) f32
    float* out = (float*)d_out;                  // (512, 256, 5, 5) f32

    const int nblocks = NK * (NC / 2);           // 65536 single-wave blocks
    roi_align_maxpool<<<nblocks, NT, 0, stream>>>(feat, rois, out);
}